// Round 8
// baseline (259.624 us; speedup 1.0000x reference)
//
#include <hip/hip_runtime.h>
#include <hip/hip_bf16.h>
#include <stdint.h>

// MultiHead attention: B=2, S=2048, D=512, H=8, dh=64. f32 I/O, bf16 MFMA core.
// NOTE: reference projects q,k,v ALL with Wq (faithful to original bug).
// v8 = v4-best attn config (bounds(256,3), setprio) + v7's Q-prescale and
//   ones-MFMA row-sums + FUSED flash-decode combine: last-arriving kv-split
//   block per (qb,bh) unit sums the 4 partials in-kernel (device-scope
//   semaphore, no spin -> no deadlock risk). 4 dispatches:
//   cvt_all -> proj_gemm -> attn(+combine) -> out_gemm.

typedef __bf16 bf16;
typedef __bf16 bvec8 __attribute__((ext_vector_type(8)));
typedef __bf16 bvec4 __attribute__((ext_vector_type(4)));
typedef float  fvec4 __attribute__((ext_vector_type(4)));
typedef float  fvec16 __attribute__((ext_vector_type(16)));
typedef int    ivec4 __attribute__((ext_vector_type(4)));

#define MFMA16(a, b, c) __builtin_amdgcn_mfma_f32_16x16x32_bf16(a, b, c, 0, 0, 0)
#define MFMA32(a, b, c) __builtin_amdgcn_mfma_f32_32x32x16_bf16(a, b, c, 0, 0, 0)

// async global->LDS, 16B per lane. HW: wave-uniform LDS base + lane*16.
__device__ __forceinline__ void async16(const void* g, void* l) {
  __builtin_amdgcn_global_load_lds(
      (__attribute__((address_space(1))) void*)(g),
      (__attribute__((address_space(3))) void*)(l), 16, 0, 0);
}

// ---------------------------------------------------------------------------
// All f32->bf16 conversions in ONE launch: q,k,v -> qkvb[3][4096][512],
// Wq -> Wq16, Wc -> Wc16. 8 elems/thread.
// ---------------------------------------------------------------------------
__global__ void cvt_all(const float* __restrict__ q, const float* __restrict__ k,
                        const float* __restrict__ v, const float* __restrict__ Wq,
                        const float* __restrict__ Wc, bf16* __restrict__ qkvb,
                        bf16* __restrict__ Wq16, bf16* __restrict__ Wc16) {
  const int t = blockIdx.x * 256 + threadIdx.x;
  const float* src;
  bf16* dst;
  size_t i;
  if (t < 786432) {                       // 3 * 2^18 threads for q,k,v
    const int which = t >> 18;
    i = (size_t)(t & 262143);
    src = (which == 0) ? q : (which == 1) ? k : v;
    dst = qkvb + ((size_t)which << 21);   // 2^21 elems per tensor
  } else if (t < 819200) {
    src = Wq; dst = Wq16; i = (size_t)(t - 786432);
  } else {
    src = Wc; dst = Wc16; i = (size_t)(t - 819200);
  }
  fvec4 a = *(const fvec4*)(src + i * 8);
  fvec4 b = *(const fvec4*)(src + i * 8 + 4);
  bvec8 o;
#pragma unroll
  for (int j = 0; j < 4; ++j) { o[j] = (bf16)a[j]; o[j + 4] = (bf16)b[j]; }
  *(bvec8*)(dst + i * 8) = o;
}

// ---------------------------------------------------------------------------
// Projection GEMM: Y[12288,512] = X @ Wq^T + bias (bf16 in, fp32 acc).
// BM=64, BN=128, BK=64; 256 threads (2x2 waves, wave tile 32x64).
// LDS XOR swizzle (16B chunk g of row r at pos g^(r&7); inverse on DMA src).
// Rows < 4096 (q third): result scaled by SC=log2(e)/8 before bf16 round.
// Rows >= 8192 (v third): store transposed per-head into Yt.
// ---------------------------------------------------------------------------
__launch_bounds__(256, 3)
__global__ void proj_gemm(const bf16* __restrict__ X, const bf16* __restrict__ W,
                          const float* __restrict__ bias, bf16* __restrict__ Y,
                          bf16* __restrict__ Yt) {
  __shared__ __attribute__((aligned(16))) char As[2][64 * 128];   // 8 KB each
  __shared__ __attribute__((aligned(16))) char Bs[2][128 * 128];  // 16 KB each

  const int tid = threadIdx.x;
  const int w = tid >> 6, l = tid & 63;
  const int wr = w >> 1, wc = w & 1;
  const int l15 = l & 15, lg = l >> 4;
  const int bm0 = blockIdx.x * 64;
  const int bn0 = blockIdx.y * 128;

  fvec4 acc[2][4] = {};

  auto stageA = [&](int buf, int k0) {
#pragma unroll
    for (int j = 0; j < 2; ++j) {
      int c = j * 256 + tid;
      int row = c >> 3, g = (c & 7) ^ (row & 7);
      async16(X + (size_t)(bm0 + row) * 512 + k0 + g * 8, &As[buf][c * 16]);
    }
  };
  auto stageB = [&](int buf, int k0) {
#pragma unroll
    for (int j = 0; j < 4; ++j) {
      int c = j * 256 + tid;
      int row = c >> 3, g = (c & 7) ^ (row & 7);
      async16(W + (size_t)(bn0 + row) * 512 + k0 + g * 8, &Bs[buf][c * 16]);
    }
  };

  stageA(0, 0);
  stageB(0, 0);
  __syncthreads();

  for (int t = 0; t < 8; ++t) {
    const int buf = t & 1;
    if (t < 7) { stageA(buf ^ 1, (t + 1) * 64); stageB(buf ^ 1, (t + 1) * 64); }
#pragma unroll
    for (int kk = 0; kk < 2; ++kk) {
      bvec8 af[2], bfr[4];
      const int g = kk * 4 + lg;
#pragma unroll
      for (int m = 0; m < 2; ++m) {
        int r = wr * 32 + m * 16 + l15;
        af[m] = *(const bvec8*)&As[buf][r * 128 + ((g ^ (r & 7)) << 4)];
      }
#pragma unroll
      for (int n = 0; n < 4; ++n) {
        int r = wc * 64 + n * 16 + l15;
        bfr[n] = *(const bvec8*)&Bs[buf][r * 128 + ((g ^ (r & 7)) << 4)];
      }
#pragma unroll
      for (int m = 0; m < 2; ++m)
#pragma unroll
        for (int n = 0; n < 4; ++n) acc[m][n] = MFMA16(af[m], bfr[n], acc[m][n]);
    }
    __syncthreads();
  }

  // Epilogue. C layout: col = lane&15, rows = (lane>>4)*4 + r.
  const bool trans = (bm0 >= 8192);
  const float scl = (bm0 < 4096) ? 0.18033688011112042f : 1.0f;  // log2(e)/8
#pragma unroll
  for (int n = 0; n < 4; ++n) {
    const int col = bn0 + wc * 64 + n * 16 + l15;
    const float bv = bias[col];
#pragma unroll
    for (int m = 0; m < 2; ++m) {
      const int row0 = bm0 + wr * 32 + m * 16 + lg * 4;
      if (!trans) {
#pragma unroll
        for (int r = 0; r < 4; ++r)
          Y[(size_t)(row0 + r) * 512 + col] = (bf16)((acc[m][n][r] + bv) * scl);
      } else {
        const int m0 = row0 - 8192;
        const int b = m0 >> 11, s = m0 & 2047;
        bvec4 v4;
#pragma unroll
        for (int r = 0; r < 4; ++r) v4[r] = (bf16)(acc[m][n][r] + bv);
        *(bvec4*)&Yt[(size_t)(b * 512 + col) * 2048 + s] = v4;
      }
    }
  }
}

// ---------------------------------------------------------------------------
// Flash attention v8. Grid (16 qb, 16 bh, 4 kv-quarters), 256 threads,
// v4-best occupancy (256,3). Swapped QK^T (Q pre-scaled by log2(e)/8) ->
// p = exp2(s) lane-local; P via v_cvt_pk_bf16_f32 + v_permlane32_swap_b32;
// PV + ones-MFMA row-sums. FUSED COMBINE: after writing partials, the
// last-arriving of the 4 kv-split blocks per (qb,bh) sums them into att.
// ---------------------------------------------------------------------------
__launch_bounds__(256, 3)
__global__ void attn_kernel(const bf16* __restrict__ qp, const bf16* __restrict__ kp,
                            const bf16* __restrict__ vt, bf16* __restrict__ po01,
                            bf16* __restrict__ po23, float* __restrict__ pl,
                            bf16* __restrict__ att, int* __restrict__ cnt) {
  __shared__ __attribute__((aligned(16))) char Ks[2][64 * 128];  // 8 KB each
  __shared__ __attribute__((aligned(16))) char Vs[2][64 * 128];
  __shared__ int sOld;

  const int tid = threadIdx.x;
  const int w = tid >> 6, l = tid & 63;
  const int l31 = l & 31, hi = l >> 5;
  const int bh = blockIdx.y, b = bh >> 3, h = bh & 7;
  const int half = blockIdx.z;
  const int kvbase = half * 512;
  const int qw0 = blockIdx.x * 128 + w * 32;

  const bf16* kbase = kp + (size_t)(b * 2048) * 512 + h * 64;
  const bf16* vbase = vt + (size_t)(b * 512 + h * 64) * 2048;

  bvec8 qf[4];
  {
    const bf16* qrow = qp + (size_t)(b * 2048 + qw0 + l31) * 512 + h * 64 + hi * 8;
#pragma unroll
    for (int ks = 0; ks < 4; ++ks) qf[ks] = *(const bvec8*)(qrow + ks * 16);
  }
  bvec8 ones;
#pragma unroll
  for (int e = 0; e < 8; ++e) ones[e] = (bf16)1.0f;

  auto stageK = [&](int buf, int kv0) {
#pragma unroll
    for (int j = 0; j < 2; ++j) {
      int c = j * 256 + tid;
      int row = c >> 3, g = (c & 7) ^ (row & 7);
      async16(kbase + (size_t)(kv0 + row) * 512 + g * 8, &Ks[buf][c * 16]);
    }
  };
  auto stageV = [&](int buf, int kv0) {
#pragma unroll
    for (int j = 0; j < 2; ++j) {
      int c = j * 256 + tid;
      int row = c >> 3, g = (c & 7) ^ (row & 7);
      async16(vbase + (size_t)row * 2048 + kv0 + g * 8, &Vs[buf][c * 16]);
    }
  };

  fvec16 oacc[2] = {};
  fvec16 lacc = {};

  stageK(0, kvbase);
  stageV(0, kvbase);
  __syncthreads();

  for (int t = 0; t < 8; ++t) {
    const int buf = t & 1;
    if (t < 7) {
      stageK(buf ^ 1, kvbase + (t + 1) * 64);
      stageV(buf ^ 1, kvbase + (t + 1) * 64);
    }

    // ---- QK^T (swapped): sac[kvb] = S^T[kv = kvb*32 + crow][q = l31] ----
    fvec16 sac[2] = {};
    __builtin_amdgcn_s_setprio(1);
#pragma unroll
    for (int ks = 0; ks < 4; ++ks) {
      const int chunk = ks * 2 + hi;
#pragma unroll
      for (int kvb = 0; kvb < 2; ++kvb) {
        const int r = kvb * 32 + l31;
        bvec8 kf = *(const bvec8*)&Ks[buf][r * 128 + ((chunk ^ (r & 7)) << 4)];
        sac[kvb] = MFMA32(kf, qf[ks], sac[kvb]);
      }
    }
    __builtin_amdgcn_s_setprio(0);

    // ---- p = exp2(s) in-register; kv(reg) = 32f+(r&3)+8*(r>>2)+4*hi ----
    ivec4 pw[4];
#pragma unroll
    for (int f = 0; f < 2; ++f) {
      float p[16];
#pragma unroll
      for (int r2 = 0; r2 < 16; ++r2) p[r2] = exp2f(sac[f][r2]);
      int wv[4][2];
#pragma unroll
      for (int m = 0; m < 4; ++m)
#pragma unroll
        for (int i = 0; i < 2; ++i)
          asm("v_cvt_pk_bf16_f32 %0, %1, %2"
              : "=v"(wv[m][i]) : "v"(p[4 * m + 2 * i]), "v"(p[4 * m + 2 * i + 1]));
#pragma unroll
      for (int i = 0; i < 2; ++i) {
        int a0 = wv[0][i], c0 = wv[1][i];
        asm volatile("v_permlane32_swap_b32 %0, %1" : "+v"(a0), "+v"(c0));
        pw[2 * f][i] = a0; pw[2 * f][2 + i] = c0;
        int a1 = wv[2][i], c1 = wv[3][i];
        asm volatile("v_permlane32_swap_b32 %0, %1" : "+v"(a1), "+v"(c1));
        pw[2 * f + 1][i] = a1; pw[2 * f + 1][2 + i] = c1;
      }
    }

    // ---- PV + row-sum: oacc += P @ Vt^T, lacc += P @ ones ----
    __builtin_amdgcn_s_setprio(1);
#pragma unroll
    for (int ks = 0; ks < 4; ++ks) {
      const bvec8 pb = __builtin_bit_cast(bvec8, pw[ks]);
      const int chunk = ks * 2 + hi;
#pragma unroll
      for (int dhb = 0; dhb < 2; ++dhb) {
        const int r = dhb * 32 + l31;
        bvec8 vf = *(const bvec8*)&Vs[buf][r * 128 + ((chunk ^ (r & 7)) << 4)];
        oacc[dhb] = MFMA32(pb, vf, oacc[dhb]);
      }
      lacc = MFMA32(pb, ones, lacc);   // all 32 cols identical = row sum
    }
    __builtin_amdgcn_s_setprio(0);
    __syncthreads();
  }

  // ---- epilogue: unnormalized O + row sums ----
  bf16* pob = ((half < 2) ? po01 : po23) + (size_t)(half & 1) * 2097152;
#pragma unroll
  for (int dhb = 0; dhb < 2; ++dhb)
#pragma unroll
    for (int r2 = 0; r2 < 16; ++r2) {
      const int q = qw0 + (r2 & 3) + 8 * (r2 >> 2) + 4 * hi;
      pob[(size_t)(b * 2048 + q) * 512 + h * 64 + dhb * 32 + l31] =
          (bf16)oacc[dhb][r2];
    }
  if (l31 == 0) {
#pragma unroll
    for (int r2 = 0; r2 < 16; ++r2) {
      const int q = qw0 + (r2 & 3) + 8 * (r2 >> 2) + 4 * hi;
      pl[half * 32768 + (b * 2048 + q) * 8 + h] = lacc[r2];
    }
  }

  // ---- semaphore: last of the 4 kv-split blocks combines this unit ----
  __threadfence();                 // make this block's partials agent-visible
  __syncthreads();                 // all waves' stores+fences done
  if (tid == 0)
    sOld = __hip_atomic_fetch_add(&cnt[bh * 16 + blockIdx.x], 1,
                                  __ATOMIC_ACQ_REL, __HIP_MEMORY_SCOPE_AGENT);
  __syncthreads();
  if (sOld == 3) {                 // we arrived last: all partials visible
    __threadfence();               // acquire side
    const bf16* pb0 = po01;
    const bf16* pb1 = po01 + 2097152;
    const bf16* pb2 = po23;
    const bf16* pb3 = po23 + 2097152;
#pragma unroll
    for (int j = 0; j < 4; ++j) {
      const int chunk = tid * 4 + j;           // 1024 chunks of 8 cols
      const int rl = chunk >> 3;               // 0..127
      const int c8 = (chunk & 7) * 8;
      const int row = b * 2048 + blockIdx.x * 128 + rl;
      const int col = h * 64 + c8;
      const float inv = 1.0f / (pl[row * 8 + h] + pl[32768 + row * 8 + h] +
                                pl[65536 + row * 8 + h] + pl[98304 + row * 8 + h]);
      const size_t off = (size_t)row * 512 + col;
      bvec8 a0 = *(const bvec8*)(pb0 + off);
      bvec8 a1 = *(const bvec8*)(pb1 + off);
      bvec8 a2 = *(const bvec8*)(pb2 + off);
      bvec8 a3 = *(const bvec8*)(pb3 + off);
      bvec8 o;
#pragma unroll
      for (int e = 0; e < 8; ++e)
        o[e] = (bf16)((((float)a0[e] + (float)a1[e]) +
                       ((float)a2[e] + (float)a3[e])) * inv);
      *(bvec8*)(att + off) = o;
    }
  }
}

// ---------------------------------------------------------------------------
// Out GEMM (verified): out = att @ Wc^T + bias (f32 out).
// ---------------------------------------------------------------------------
__launch_bounds__(256, 3)
__global__ void out_gemm(const bf16* __restrict__ X, const bf16* __restrict__ W,
                         const float* __restrict__ bias, float* __restrict__ Y) {
  __shared__ __attribute__((aligned(16))) char As[2][64 * 128];   // 8 KB each
  __shared__ __attribute__((aligned(16))) char Bs[2][128 * 128];  // 16 KB each

  const int tid = threadIdx.x;
  const int w = tid >> 6, l = tid & 63;
  const int wr = w >> 1, wc = w & 1;
  const int l15 = l & 15, lg = l >> 4;
  const int bm0 = blockIdx.x * 64;
  const int bn0 = blockIdx.y * 128;

  fvec4 acc[2][4] = {};

  auto stageA = [&](int buf, int k0) {
#pragma unroll
    for (int j = 0; j < 2; ++j) {
      int c = j * 256 + tid;
      int row = c >> 3, g = (c & 7) ^ (row & 7);
      async16(X + (size_t)(bm0 + row) * 512 + k0 + g * 8, &As[buf][c * 16]);
    }
  };
  auto stageB = [&](int buf, int k0) {
#pragma unroll
    for (int j = 0; j < 4; ++j) {
      int c = j * 256 + tid;
      int row = c >> 3, g = (c & 7) ^ (row & 7);
      async16(W + (size_t)(bn0 + row) * 512 + k0 + g * 8, &Bs[buf][c * 16]);
    }
  };

  stageA(0, 0);
  stageB(0, 0);
  __syncthreads();

  for (int t = 0; t < 8; ++t) {
    const int buf = t & 1;
    if (t < 7) { stageA(buf ^ 1, (t + 1) * 64); stageB(buf ^ 1, (t + 1) * 64); }
#pragma unroll
    for (int kk = 0; kk < 2; ++kk) {
      bvec8 af[2], bfr[4];
      const int g = kk * 4 + lg;
#pragma unroll
      for (int m = 0; m < 2; ++m) {
        int r = wr * 32 + m * 16 + l15;
        af[m] = *(const bvec8*)&As[buf][r * 128 + ((g ^ (r & 7)) << 4)];
      }
#pragma unroll
      for (int n = 0; n < 4; ++n) {
        int r = wc * 64 + n * 16 + l15;
        bfr[n] = *(const bvec8*)&Bs[buf][r * 128 + ((g ^ (r & 7)) << 4)];
      }
#pragma unroll
      for (int m = 0; m < 2; ++m)
#pragma unroll
        for (int n = 0; n < 4; ++n) acc[m][n] = MFMA16(af[m], bfr[n], acc[m][n]);
    }
    __syncthreads();
  }

#pragma unroll
  for (int n = 0; n < 4; ++n) {
    const int col = bn0 + wc * 64 + n * 16 + l15;
    const float bv = bias[col];
#pragma unroll
    for (int m = 0; m < 2; ++m) {
      const int row0 = bm0 + wr * 32 + m * 16 + lg * 4;
#pragma unroll
      for (int r = 0; r < 4; ++r)
        Y[(size_t)(row0 + r) * 512 + col] = acc[m][n][r] + bv;
    }
  }
}

// ---------------------------------------------------------------------------
extern "C" void kernel_launch(void* const* d_in, const int* in_sizes, int n_in,
                              void* d_out, int out_size, void* d_ws, size_t ws_size,
                              hipStream_t stream) {
  const float* q   = (const float*)d_in[0];
  const float* k   = (const float*)d_in[1];
  const float* v   = (const float*)d_in[2];
  const float* Wq  = (const float*)d_in[3];
  const float* Wqb = (const float*)d_in[4];
  const float* Wc  = (const float*)d_in[5];
  const float* Wcb = (const float*)d_in[6];
  float* out = (float*)d_out;

  char* ws = (char*)d_ws;
  const size_t MB = 1u << 20;
  bf16* qkvb = (bf16*)(ws);                        // [3][4096][512], 0..12MB
  bf16* po01 = (bf16*)(ws);                        // [2][4096][512] reuses qkvb
  bf16* att  = (bf16*)(ws + 8 * MB);               // [4096][512], 8..12MB
  bf16* Wq16 = (bf16*)(ws + 12 * MB);              // 0.5MB
  bf16* Wc16 = (bf16*)(ws + 12 * MB + 512 * 1024); // 0.5MB
  bf16* qkp  = (bf16*)(ws + 13 * MB);              // [8192][512], 13..21MB
  bf16* vt   = (bf16*)(ws + 21 * MB);              // [b][h][dh][2048], 21..25MB
  bf16* po23 = (bf16*)(ws + 25 * MB);              // [2][4096][512], 25..33MB
  float* pl  = (float*)(ws + 33 * MB);             // [4][4096][8] f32, 512KB
  int*   cnt = (int*)(ws + 34 * MB);               // [256] semaphores, 1KB

  hipMemsetAsync(cnt, 0, 256 * sizeof(int), stream);

  dim3 bb(256);
  hipLaunchKernelGGL(cvt_all, dim3(3328), bb, 0, stream, q, k, v, Wq, Wc,
                     qkvb, Wq16, Wc16);
  hipLaunchKernelGGL(proj_gemm, dim3(192, 4), bb, 0, stream,
                     qkvb, Wq16, Wqb, qkp, vt);
  hipLaunchKernelGGL(attn_kernel, dim3(16, 16, 4), bb, 0, stream,
                     qkp, qkp + 2097152, vt, po01, po23, pl, att, cnt);
  hipLaunchKernelGGL(out_gemm, dim3(64, 4), bb, 0, stream,
                     att, Wc16, Wcb, out);
}

// Round 9
// 69.402 us; speedup vs baseline: 3.7409x; 3.7409x over previous
//
#include <hip/hip_runtime.h>
#include <hip/hip_bf16.h>
#include <stdint.h>

// MultiHead attention: B=2, S=2048, D=512, H=8, dh=64. f32 I/O, bf16 MFMA core.
// NOTE: reference projects q,k,v ALL with Wq (faithful to original bug).
// v9 = v7 structure (5 dispatches; fused-combine REVERTED: its device-scope
//   fences forced uncached writes, 6x attn slowdown). NEW in attn: triple-
//   buffered K/V staging, prefetch 2 tiles ahead, raw s_barrier with COUNTED
//   s_waitcnt vmcnt(4) (T3/T4-lite) -- prefetch stays in flight across the
//   barrier instead of the vmcnt(0) drain hipcc emits for __syncthreads.

typedef __bf16 bf16;
typedef __bf16 bvec8 __attribute__((ext_vector_type(8)));
typedef __bf16 bvec4 __attribute__((ext_vector_type(4)));
typedef float  fvec4 __attribute__((ext_vector_type(4)));
typedef float  fvec16 __attribute__((ext_vector_type(16)));
typedef int    ivec4 __attribute__((ext_vector_type(4)));

#define MFMA16(a, b, c) __builtin_amdgcn_mfma_f32_16x16x32_bf16(a, b, c, 0, 0, 0)
#define MFMA32(a, b, c) __builtin_amdgcn_mfma_f32_32x32x16_bf16(a, b, c, 0, 0, 0)

// async global->LDS, 16B per lane. HW: wave-uniform LDS base + lane*16.
__device__ __forceinline__ void async16(const void* g, void* l) {
  __builtin_amdgcn_global_load_lds(
      (__attribute__((address_space(1))) void*)(g),
      (__attribute__((address_space(3))) void*)(l), 16, 0, 0);
}

// ---------------------------------------------------------------------------
// All f32->bf16 conversions in ONE launch: q,k,v -> qkvb[3][4096][512],
// Wq -> Wq16, Wc -> Wc16. 8 elems/thread.
// ---------------------------------------------------------------------------
__global__ void cvt_all(const float* __restrict__ q, const float* __restrict__ k,
                        const float* __restrict__ v, const float* __restrict__ Wq,
                        const float* __restrict__ Wc, bf16* __restrict__ qkvb,
                        bf16* __restrict__ Wq16, bf16* __restrict__ Wc16) {
  const int t = blockIdx.x * 256 + threadIdx.x;
  const float* src;
  bf16* dst;
  size_t i;
  if (t < 786432) {                       // 3 * 2^18 threads for q,k,v
    const int which = t >> 18;
    i = (size_t)(t & 262143);
    src = (which == 0) ? q : (which == 1) ? k : v;
    dst = qkvb + ((size_t)which << 21);   // 2^21 elems per tensor
  } else if (t < 819200) {
    src = Wq; dst = Wq16; i = (size_t)(t - 786432);
  } else {
    src = Wc; dst = Wc16; i = (size_t)(t - 819200);
  }
  fvec4 a = *(const fvec4*)(src + i * 8);
  fvec4 b = *(const fvec4*)(src + i * 8 + 4);
  bvec8 o;
#pragma unroll
  for (int j = 0; j < 4; ++j) { o[j] = (bf16)a[j]; o[j + 4] = (bf16)b[j]; }
  *(bvec8*)(dst + i * 8) = o;
}

// ---------------------------------------------------------------------------
// Projection GEMM: Y[12288,512] = X @ Wq^T + bias (bf16 in, fp32 acc).
// BM=64, BN=128, BK=64; 256 threads (2x2 waves, wave tile 32x64).
// LDS XOR swizzle (16B chunk g of row r at pos g^(r&7); inverse on DMA src).
// Rows < 4096 (q third): result scaled by SC=log2(e)/8 before bf16 round.
// Rows >= 8192 (v third): store transposed per-head into Yt.
// ---------------------------------------------------------------------------
__launch_bounds__(256, 3)
__global__ void proj_gemm(const bf16* __restrict__ X, const bf16* __restrict__ W,
                          const float* __restrict__ bias, bf16* __restrict__ Y,
                          bf16* __restrict__ Yt) {
  __shared__ __attribute__((aligned(16))) char As[2][64 * 128];   // 8 KB each
  __shared__ __attribute__((aligned(16))) char Bs[2][128 * 128];  // 16 KB each

  const int tid = threadIdx.x;
  const int w = tid >> 6, l = tid & 63;
  const int wr = w >> 1, wc = w & 1;
  const int l15 = l & 15, lg = l >> 4;
  const int bm0 = blockIdx.x * 64;
  const int bn0 = blockIdx.y * 128;

  fvec4 acc[2][4] = {};

  auto stageA = [&](int buf, int k0) {
#pragma unroll
    for (int j = 0; j < 2; ++j) {
      int c = j * 256 + tid;
      int row = c >> 3, g = (c & 7) ^ (row & 7);
      async16(X + (size_t)(bm0 + row) * 512 + k0 + g * 8, &As[buf][c * 16]);
    }
  };
  auto stageB = [&](int buf, int k0) {
#pragma unroll
    for (int j = 0; j < 4; ++j) {
      int c = j * 256 + tid;
      int row = c >> 3, g = (c & 7) ^ (row & 7);
      async16(W + (size_t)(bn0 + row) * 512 + k0 + g * 8, &Bs[buf][c * 16]);
    }
  };

  stageA(0, 0);
  stageB(0, 0);
  __syncthreads();

  for (int t = 0; t < 8; ++t) {
    const int buf = t & 1;
    if (t < 7) { stageA(buf ^ 1, (t + 1) * 64); stageB(buf ^ 1, (t + 1) * 64); }
#pragma unroll
    for (int kk = 0; kk < 2; ++kk) {
      bvec8 af[2], bfr[4];
      const int g = kk * 4 + lg;
#pragma unroll
      for (int m = 0; m < 2; ++m) {
        int r = wr * 32 + m * 16 + l15;
        af[m] = *(const bvec8*)&As[buf][r * 128 + ((g ^ (r & 7)) << 4)];
      }
#pragma unroll
      for (int n = 0; n < 4; ++n) {
        int r = wc * 64 + n * 16 + l15;
        bfr[n] = *(const bvec8*)&Bs[buf][r * 128 + ((g ^ (r & 7)) << 4)];
      }
#pragma unroll
      for (int m = 0; m < 2; ++m)
#pragma unroll
        for (int n = 0; n < 4; ++n) acc[m][n] = MFMA16(af[m], bfr[n], acc[m][n]);
    }
    __syncthreads();
  }

  // Epilogue. C layout: col = lane&15, rows = (lane>>4)*4 + r.
  const bool trans = (bm0 >= 8192);
  const float scl = (bm0 < 4096) ? 0.18033688011112042f : 1.0f;  // log2(e)/8
#pragma unroll
  for (int n = 0; n < 4; ++n) {
    const int col = bn0 + wc * 64 + n * 16 + l15;
    const float bv = bias[col];
#pragma unroll
    for (int m = 0; m < 2; ++m) {
      const int row0 = bm0 + wr * 32 + m * 16 + lg * 4;
      if (!trans) {
#pragma unroll
        for (int r = 0; r < 4; ++r)
          Y[(size_t)(row0 + r) * 512 + col] = (bf16)((acc[m][n][r] + bv) * scl);
      } else {
        const int m0 = row0 - 8192;
        const int b = m0 >> 11, s = m0 & 2047;
        bvec4 v4;
#pragma unroll
        for (int r = 0; r < 4; ++r) v4[r] = (bf16)(acc[m][n][r] + bv);
        *(bvec4*)&Yt[(size_t)(b * 512 + col) * 2048 + s] = v4;
      }
    }
  }
}

// ---------------------------------------------------------------------------
// Flash attention v9. Grid (16 qb, 16 bh, 4 kv-quarters), 256 threads.
// Triple-buffered K/V (3 x 16 KB = 48 KB), prefetch 2 tiles ahead, raw
// s_barrier with counted vmcnt(4): each wave waits only its OWN stage(t+1)
// loads (4/wave) before the barrier; barrier joins all waves => tile t+1
// fully staged, while stage(t+2)'s 4 loads stay in flight (no drain).
// Swapped QK^T (Q pre-scaled log2(e)/8) -> p=exp2(s) lane-local; P via
// v_cvt_pk_bf16_f32 + permlane32_swap; PV + ones-MFMA row sums.
// ---------------------------------------------------------------------------
__launch_bounds__(256, 3)
__global__ void attn_kernel(const bf16* __restrict__ qp, const bf16* __restrict__ kp,
                            const bf16* __restrict__ vt, bf16* __restrict__ po01,
                            bf16* __restrict__ po23, float* __restrict__ pl) {
  __shared__ __attribute__((aligned(16))) char Ks[3][64 * 128];  // 8 KB each
  __shared__ __attribute__((aligned(16))) char Vs[3][64 * 128];

  const int tid = threadIdx.x;
  const int w = tid >> 6, l = tid & 63;
  const int l31 = l & 31, hi = l >> 5;
  const int bh = blockIdx.y, b = bh >> 3, h = bh & 7;
  const int half = blockIdx.z;
  const int kvbase = half * 512;
  const int qw0 = blockIdx.x * 128 + w * 32;

  const bf16* kbase = kp + (size_t)(b * 2048) * 512 + h * 64;
  const bf16* vbase = vt + (size_t)(b * 512 + h * 64) * 2048;

  bvec8 qf[4];
  {
    const bf16* qrow = qp + (size_t)(b * 2048 + qw0 + l31) * 512 + h * 64 + hi * 8;
#pragma unroll
    for (int ks = 0; ks < 4; ++ks) qf[ks] = *(const bvec8*)(qrow + ks * 16);
  }
  bvec8 ones;
#pragma unroll
  for (int e = 0; e < 8; ++e) ones[e] = (bf16)1.0f;

  // one stage = 2 K-loads + 2 V-loads per thread (vmcnt 4/stage/wave)
  auto stage = [&](int buf, int kv0) {
#pragma unroll
    for (int j = 0; j < 2; ++j) {
      int c = j * 256 + tid;
      int row = c >> 3, g = (c & 7) ^ (row & 7);
      async16(kbase + (size_t)(kv0 + row) * 512 + g * 8, &Ks[buf][c * 16]);
    }
#pragma unroll
    for (int j = 0; j < 2; ++j) {
      int c = j * 256 + tid;
      int row = c >> 3, g = (c & 7) ^ (row & 7);
      async16(vbase + (size_t)row * 2048 + kv0 + g * 8, &Vs[buf][c * 16]);
    }
  };

  fvec16 oacc[2] = {};
  fvec16 lacc = {};

  stage(0, kvbase);
  stage(1, kvbase + 64);
  asm volatile("s_waitcnt vmcnt(4)" ::: "memory");   // stage(0) complete
  __builtin_amdgcn_sched_barrier(0);
  __builtin_amdgcn_s_barrier();

  for (int t = 0; t < 8; ++t) {
    const int buf = t % 3;
    if (t < 6) stage((t + 2) % 3, kvbase + (t + 2) * 64);

    // ---- QK^T (swapped): sac[kvb] = S^T[kv = kvb*32 + crow][q = l31] ----
    fvec16 sac[2] = {};
    __builtin_amdgcn_s_setprio(1);
#pragma unroll
    for (int ks = 0; ks < 4; ++ks) {
      const int chunk = ks * 2 + hi;
#pragma unroll
      for (int kvb = 0; kvb < 2; ++kvb) {
        const int r = kvb * 32 + l31;
        bvec8 kf = *(const bvec8*)&Ks[buf][r * 128 + ((chunk ^ (r & 7)) << 4)];
        sac[kvb] = MFMA32(kf, qf[ks], sac[kvb]);
      }
    }
    __builtin_amdgcn_s_setprio(0);

    // ---- p = exp2(s) in-register; kv(reg) = 32f+(r&3)+8*(r>>2)+4*hi ----
    ivec4 pw[4];
#pragma unroll
    for (int f = 0; f < 2; ++f) {
      float p[16];
#pragma unroll
      for (int r2 = 0; r2 < 16; ++r2) p[r2] = exp2f(sac[f][r2]);
      int wv[4][2];
#pragma unroll
      for (int m = 0; m < 4; ++m)
#pragma unroll
        for (int i = 0; i < 2; ++i)
          asm("v_cvt_pk_bf16_f32 %0, %1, %2"
              : "=v"(wv[m][i]) : "v"(p[4 * m + 2 * i]), "v"(p[4 * m + 2 * i + 1]));
#pragma unroll
      for (int i = 0; i < 2; ++i) {
        int a0 = wv[0][i], c0 = wv[1][i];
        asm volatile("v_permlane32_swap_b32 %0, %1" : "+v"(a0), "+v"(c0));
        pw[2 * f][i] = a0; pw[2 * f][2 + i] = c0;
        int a1 = wv[2][i], c1 = wv[3][i];
        asm volatile("v_permlane32_swap_b32 %0, %1" : "+v"(a1), "+v"(c1));
        pw[2 * f + 1][i] = a1; pw[2 * f + 1][2 + i] = c1;
      }
    }

    // ---- PV + row-sum: oacc += P @ Vt^T, lacc += P @ ones ----
    __builtin_amdgcn_s_setprio(1);
#pragma unroll
    for (int ks = 0; ks < 4; ++ks) {
      const bvec8 pb = __builtin_bit_cast(bvec8, pw[ks]);
      const int chunk = ks * 2 + hi;
#pragma unroll
      for (int dhb = 0; dhb < 2; ++dhb) {
        const int r = dhb * 32 + l31;
        bvec8 vf = *(const bvec8*)&Vs[buf][r * 128 + ((chunk ^ (r & 7)) << 4)];
        oacc[dhb] = MFMA32(pb, vf, oacc[dhb]);
      }
      lacc = MFMA32(pb, ones, lacc);   // all 32 cols identical = row sum
    }
    __builtin_amdgcn_s_setprio(0);

    // ---- counted-vmcnt barrier: retire stage(t+1), keep stage(t+2) ----
    if (t < 7) {
      if (t < 6) asm volatile("s_waitcnt vmcnt(4)" ::: "memory");
      else       asm volatile("s_waitcnt vmcnt(0)" ::: "memory");
      __builtin_amdgcn_sched_barrier(0);
      __builtin_amdgcn_s_barrier();
    }
  }

  // ---- epilogue: unnormalized O + row sums ----
  bf16* pob = ((half < 2) ? po01 : po23) + (size_t)(half & 1) * 2097152;
#pragma unroll
  for (int dhb = 0; dhb < 2; ++dhb)
#pragma unroll
    for (int r2 = 0; r2 < 16; ++r2) {
      const int q = qw0 + (r2 & 3) + 8 * (r2 >> 2) + 4 * hi;
      pob[(size_t)(b * 2048 + q) * 512 + h * 64 + dhb * 32 + l31] =
          (bf16)oacc[dhb][r2];
    }
  if (l31 == 0) {
#pragma unroll
    for (int r2 = 0; r2 < 16; ++r2) {
      const int q = qw0 + (r2 & 3) + 8 * (r2 >> 2) + 4 * hi;
      pl[half * 32768 + (b * 2048 + q) * 8 + h] = lacc[r2];
    }
  }
}

// ---------------------------------------------------------------------------
// Combine 4 kv-quarters: att = (sum O_i) / (sum l_i). 1024 blocks x 256.
// ---------------------------------------------------------------------------
__global__ void combine_kernel(const bf16* __restrict__ po01, const bf16* __restrict__ po23,
                               const float* __restrict__ pl, bf16* __restrict__ att) {
  const int t = blockIdx.x * 256 + threadIdx.x;
  const int row = t >> 6;
  const int c8 = (t & 63) << 3;
  const int h = c8 >> 6;
  const float inv = 1.0f / (pl[row * 8 + h] + pl[32768 + row * 8 + h] +
                            pl[65536 + row * 8 + h] + pl[98304 + row * 8 + h]);
  bvec8 a0 = *(const bvec8*)(po01 + (size_t)row * 512 + c8);
  bvec8 a1 = *(const bvec8*)(po01 + 2097152 + (size_t)row * 512 + c8);
  bvec8 a2 = *(const bvec8*)(po23 + (size_t)row * 512 + c8);
  bvec8 a3 = *(const bvec8*)(po23 + 2097152 + (size_t)row * 512 + c8);
  bvec8 o;
#pragma unroll
  for (int j = 0; j < 8; ++j)
    o[j] = (bf16)((((float)a0[j] + (float)a1[j]) + ((float)a2[j] + (float)a3[j])) * inv);
  *(bvec8*)(att + (size_t)row * 512 + c8) = o;
}

// ---------------------------------------------------------------------------
// Out GEMM (verified): out = att @ Wc^T + bias (f32 out).
// ---------------------------------------------------------------------------
__launch_bounds__(256, 3)
__global__ void out_gemm(const bf16* __restrict__ X, const bf16* __restrict__ W,
                         const float* __restrict__ bias, float* __restrict__ Y) {
  __shared__ __attribute__((aligned(16))) char As[2][64 * 128];   // 8 KB each
  __shared__ __attribute__((aligned(16))) char Bs[2][128 * 128];  // 16 KB each

  const int tid = threadIdx.x;
  const int w = tid >> 6, l = tid & 63;
  const int wr = w >> 1, wc = w & 1;
  const int l15 = l & 15, lg = l >> 4;
  const int bm0 = blockIdx.x * 64;
  const int bn0 = blockIdx.y * 128;

  fvec4 acc[2][4] = {};

  auto stageA = [&](int buf, int k0) {
#pragma unroll
    for (int j = 0; j < 2; ++j) {
      int c = j * 256 + tid;
      int row = c >> 3, g = (c & 7) ^ (row & 7);
      async16(X + (size_t)(bm0 + row) * 512 + k0 + g * 8, &As[buf][c * 16]);
    }
  };
  auto stageB = [&](int buf, int k0) {
#pragma unroll
    for (int j = 0; j < 4; ++j) {
      int c = j * 256 + tid;
      int row = c >> 3, g = (c & 7) ^ (row & 7);
      async16(W + (size_t)(bn0 + row) * 512 + k0 + g * 8, &Bs[buf][c * 16]);
    }
  };

  stageA(0, 0);
  stageB(0, 0);
  __syncthreads();

  for (int t = 0; t < 8; ++t) {
    const int buf = t & 1;
    if (t < 7) { stageA(buf ^ 1, (t + 1) * 64); stageB(buf ^ 1, (t + 1) * 64); }
#pragma unroll
    for (int kk = 0; kk < 2; ++kk) {
      bvec8 af[2], bfr[4];
      const int g = kk * 4 + lg;
#pragma unroll
      for (int m = 0; m < 2; ++m) {
        int r = wr * 32 + m * 16 + l15;
        af[m] = *(const bvec8*)&As[buf][r * 128 + ((g ^ (r & 7)) << 4)];
      }
#pragma unroll
      for (int n = 0; n < 4; ++n) {
        int r = wc * 64 + n * 16 + l15;
        bfr[n] = *(const bvec8*)&Bs[buf][r * 128 + ((g ^ (r & 7)) << 4)];
      }
#pragma unroll
      for (int m = 0; m < 2; ++m)
#pragma unroll
        for (int n = 0; n < 4; ++n) acc[m][n] = MFMA16(af[m], bfr[n], acc[m][n]);
    }
    __syncthreads();
  }

#pragma unroll
  for (int n = 0; n < 4; ++n) {
    const int col = bn0 + wc * 64 + n * 16 + l15;
    const float bv = bias[col];
#pragma unroll
    for (int m = 0; m < 2; ++m) {
      const int row0 = bm0 + wr * 32 + m * 16 + lg * 4;
#pragma unroll
      for (int r = 0; r < 4; ++r)
        Y[(size_t)(row0 + r) * 512 + col] = acc[m][n][r] + bv;
    }
  }
}

// ---------------------------------------------------------------------------
extern "C" void kernel_launch(void* const* d_in, const int* in_sizes, int n_in,
                              void* d_out, int out_size, void* d_ws, size_t ws_size,
                              hipStream_t stream) {
  const float* q   = (const float*)d_in[0];
  const float* k   = (const float*)d_in[1];
  const float* v   = (const float*)d_in[2];
  const float* Wq  = (const float*)d_in[3];
  const float* Wqb = (const float*)d_in[4];
  const float* Wc  = (const float*)d_in[5];
  const float* Wcb = (const float*)d_in[6];
  float* out = (float*)d_out;

  char* ws = (char*)d_ws;
  const size_t MB = 1u << 20;
  bf16* qkvb = (bf16*)(ws);                        // [3][4096][512], 0..12MB
  bf16* po01 = (bf16*)(ws);                        // [2][4096][512] reuses qkvb
  bf16* att  = (bf16*)(ws + 8 * MB);               // [4096][512], 8..12MB
  bf16* Wq16 = (bf16*)(ws + 12 * MB);              // 0.5MB
  bf16* Wc16 = (bf16*)(ws + 12 * MB + 512 * 1024); // 0.5MB
  bf16* qkp  = (bf16*)(ws + 13 * MB);              // [8192][512], 13..21MB
  bf16* vt   = (bf16*)(ws + 21 * MB);              // [b][h][dh][2048], 21..25MB
  bf16* po23 = (bf16*)(ws + 25 * MB);              // [2][4096][512], 25..33MB
  float* pl  = (float*)(ws + 33 * MB);             // [4][4096][8] f32, 512KB

  dim3 bb(256);
  hipLaunchKernelGGL(cvt_all, dim3(3328), bb, 0, stream, q, k, v, Wq, Wc,
                     qkvb, Wq16, Wc16);
  hipLaunchKernelGGL(proj_gemm, dim3(192, 4), bb, 0, stream,
                     qkvb, Wq16, Wqb, qkp, vt);
  hipLaunchKernelGGL(attn_kernel, dim3(16, 16, 4), bb, 0, stream,
                     qkp, qkp + 2097152, vt, po01, po23, pl);
  hipLaunchKernelGGL(combine_kernel, dim3(1024), bb, 0, stream,
                     po01, po23, pl, att);
  hipLaunchKernelGGL(out_gemm, dim3(64, 4), bb, 0, stream,
                     att, Wc16, Wcb, out);
}